// Round 8
// baseline (152.104 us; speedup 1.0000x reference)
//
#include <hip/hip_runtime.h>
#include <math.h>

#define B_ 8
#define N_ 32
#define M_ 32
#define HW 192

typedef __attribute__((ext_vector_type(8))) short short8;
typedef __attribute__((ext_vector_type(4))) float float4_;

__device__ inline unsigned short f2bf(float f) {
    unsigned int b = __float_as_uint(f);
    b += 0x7FFF + ((b >> 16) & 1);   // RNE
    return (unsigned short)(b >> 16);
}
__device__ inline float bf2f(unsigned short u) {
    return __uint_as_float((unsigned int)u << 16);
}

union U8 { short8 s; unsigned int u[4]; };

// ---- transpose+pool (blocks 0..1535, one per (b,h) row) + prep (block 1536) ----
// x_t[b][h][w][n] bf16 (channel-last); partial[b][h][n] = row sum
// a1A[c][lane][j] : o=lane&15 (o<9 real, else 0), n=(lane>>4)*8+j, p=c
// wA [c][mt][lane][j] : m=mt*16+(lane&15), n=(lane>>4)*8+j, p=c
__global__ __launch_bounds__(192) void transpose_pool_kernel(
    const float* __restrict__ x, const float* __restrict__ a1w,
    const float* __restrict__ weight, float* __restrict__ partial,
    unsigned short* __restrict__ a1A, unsigned short* __restrict__ wA,
    unsigned short* __restrict__ xt) {
    const int id = blockIdx.x;
    const int tid = threadIdx.x;
    if (id == 1536) {  // prep block: build bf16 MFMA A-fragments
        for (int idx = tid; idx < 9 * 512; idx += 192) {
            int j = idx & 7, l = (idx >> 3) & 63, c = idx >> 9;
            int o = l & 15, n = (l >> 4) * 8 + j;
            float v = (o < 9) ? a1w[(o * N_ + n) * 9 + c] : 0.f;
            a1A[idx] = f2bf(v);
        }
        for (int idx = tid; idx < 9 * 1024; idx += 192) {
            int j = idx & 7, l = (idx >> 3) & 63, mt = (idx >> 9) & 1, c = idx >> 10;
            int m = mt * 16 + (l & 15), n = (l >> 4) * 8 + j;
            wA[idx] = f2bf(weight[(m * N_ + n) * 9 + c]);
        }
        return;
    }
    // b = id&7 keeps one image per XCD (matches laconv's consumer swizzle)
    const int b = id & 7, h = id >> 3;  // h in 0..191
    const float* xb = x + (size_t)b * N_ * (HW * HW) + h * HW + tid;
    float v[32];
#pragma unroll
    for (int n = 0; n < 32; ++n) v[n] = xb[n * (HW * HW)];
    U8 tq[4];
#pragma unroll
    for (int q = 0; q < 4; ++q)
#pragma unroll
        for (int i = 0; i < 4; ++i)
            tq[q].u[i] = (unsigned)f2bf(v[q * 8 + 2 * i]) |
                         ((unsigned)f2bf(v[q * 8 + 2 * i + 1]) << 16);
    short8* dst = (short8*)&xt[(((size_t)b * HW + h) * HW + tid) * 32];
    dst[0] = tq[0].s; dst[1] = tq[1].s; dst[2] = tq[2].s; dst[3] = tq[3].s;

    // per-channel row sums: wave shuffle reduce, then cross-wave via LDS
    __shared__ float red[3][32];
    const int wv = tid >> 6, lane = tid & 63;
#pragma unroll
    for (int n = 0; n < 32; ++n) {
        float s = v[n];
#pragma unroll
        for (int off = 32; off > 0; off >>= 1) s += __shfl_down(s, off, 64);
        if (lane == 0) red[wv][n] = s;
    }
    __syncthreads();
    if (tid < 32)
        partial[((size_t)b * HW + h) * 32 + tid] =
            red[0][tid] + red[1][tid] + red[2][tid];
}

// ---------- fused MFMA kernel: attention1 + attended conv + bias ----------
__global__ __launch_bounds__(256, 6) void laconv_kernel(
    const unsigned short* __restrict__ xt, const float* __restrict__ a1b,
    const float* __restrict__ a2w, const float* __restrict__ a2b,
    const float* __restrict__ a3w, const float* __restrict__ a3b,
    const unsigned short* __restrict__ a1A, const unsigned short* __restrict__ wA,
    const float* __restrict__ partial, const float* __restrict__ b1w,
    const float* __restrict__ b1b, const float* __restrict__ b2w,
    const float* __restrict__ b2b, float* __restrict__ out) {
    // xs[grp][pos][j]: grp = n/8, pos = r*18+cc (18x18 tile+halo), j = n%8
    __shared__ __align__(16) unsigned short xs[4 * 324 * 8];  // 20736 B
    __shared__ unsigned short att_s[9 * 264];                 //  4752 B (bf16)
    __shared__ float pooled_s[N_], hsh[M_];
    __shared__ __align__(16) float bias_lds[M_];              // ~25.9 KB -> 6 blk/CU

    // XCD-affinity swizzle: batch = id&7, tiles of one image stay per-XCD
    const int id = blockIdx.x;
    const int b = id & 7;
    const int t = id >> 3;
    const int bx = t % 12, by = t / 12;
    const int th0 = by * 16, tw0 = bx * 16;
    const int tid = threadIdx.x;
    const int wv = tid >> 6, lane = tid & 63;
    const int tx = lane & 15, ks = lane >> 4;

    // ---- stage: 64B bf16 channel rows from x_t -> xs (no conversion) ----
    const unsigned short* xtb = xt + (size_t)b * (HW * HW) * 32;
    short8 ra[4], rb[4];
    {
        int pos = tid, r = pos / 18, cc = pos - r * 18;
        int h = th0 + r - 1, w = tw0 + cc - 1;
        if (((unsigned)h < HW) && ((unsigned)w < HW)) {
            const short8* src = (const short8*)&xtb[(size_t)(h * HW + w) * 32];
            ra[0] = src[0]; ra[1] = src[1]; ra[2] = src[2]; ra[3] = src[3];
        } else {
#pragma unroll
            for (int g = 0; g < 4; ++g) ra[g] = (short8)(short)0;
        }
    }
    const bool hasB = tid < 324 - 256;
    if (hasB) {
        int pos = 256 + tid, r = pos / 18, cc = pos - r * 18;
        int h = th0 + r - 1, w = tw0 + cc - 1;
        if (((unsigned)h < HW) && ((unsigned)w < HW)) {
            const short8* src = (const short8*)&xtb[(size_t)(h * HW + w) * 32];
            rb[0] = src[0]; rb[1] = src[1]; rb[2] = src[2]; rb[3] = src[3];
        } else {
#pragma unroll
            for (int g = 0; g < 4; ++g) rb[g] = (short8)(short)0;
        }
    }
    // pooled[b][n] from per-row partials (contiguous, L2-hot; hidden here)
    float ps = 0.f;
    if (tid < N_) {
        for (int c = 0; c < HW; ++c) ps += partial[((size_t)b * HW + c) * 32 + tid];
    }
#pragma unroll
    for (int g = 0; g < 4; ++g) *(short8*)&xs[g * 2592 + tid * 8] = ra[g];
    if (hasB) {
#pragma unroll
        for (int g = 0; g < 4; ++g) *(short8*)&xs[g * 2592 + (256 + tid) * 8] = rb[g];
    }
    if (tid < N_) pooled_s[tid] = ps * (1.f / (HW * HW));
    __syncthreads();

    // bias MLP stage 1 (tiny; hsh read only after next barrier)
    if (tid < M_) {
        float s = b1b[tid];
#pragma unroll
        for (int n = 0; n < N_; n++) s += pooled_s[n] * b1w[tid * N_ + n];
        hsh[tid] = fmaxf(s, 0.f);
    }

    // per-lane base into xs: pixel (ty = wv*4+g, tx), k-slot ks
    const int pb = ks * 2592 + wv * 576 + tx * 8;
    const float4_ zero4 = {0.f, 0.f, 0.f, 0.f};

    // ---- attention1 conv via MFMA: aacc[o=ks*4+reg][pix=tx] per group ----
    float4_ aacc[4];
#pragma unroll
    for (int g = 0; g < 4; ++g) aacc[g] = zero4;
#pragma unroll
    for (int c = 0; c < 9; ++c) {
        short8 aA = ((const short8*)a1A)[c * 64 + lane];
        const int coff = (c / 3) * 144 + (c % 3) * 8;
#pragma unroll
        for (int g = 0; g < 4; ++g) {
            short8 bP = *(const short8*)&xs[pb + g * 144 + coff];
            aacc[g] = __builtin_amdgcn_mfma_f32_16x16x32_bf16(aA, bP, aacc[g], 0, 0, 0);
        }
    }
    // write raw conv results (bf16) to att_s[o][pix]
#pragma unroll
    for (int g = 0; g < 4; ++g) {
#pragma unroll
        for (int reg = 0; reg < 4; ++reg) {
            int o = ks * 4 + reg;
            if (o < 9) att_s[o * 264 + (wv * 4 + g) * 16 + tx] = f2bf(aacc[g][reg]);
        }
    }
    __syncthreads();

    // bias MLP stage 2 (bias_lds read only after the att sync below)
    if (tid < M_) {
        float s2 = b2b[tid];
#pragma unroll
        for (int q = 0; q < M_; q++) s2 += hsh[q] * b2w[tid * M_ + q];
        bias_lds[tid] = s2;
    }

    // ---- per-pixel MLP 9->9->9 + sigmoid; column-local, no extra barrier ----
    float t1[9], t2[9], attv[9];
#pragma unroll
    for (int o = 0; o < 9; ++o)
        t1[o] = fmaxf(bf2f(att_s[o * 264 + tid]) + a1b[o], 0.f);
#pragma unroll
    for (int o2 = 0; o2 < 9; ++o2) {
        float s = a2b[o2];
#pragma unroll
        for (int o = 0; o < 9; ++o) s += a2w[o2 * 9 + o] * t1[o];
        t2[o2] = fmaxf(s, 0.f);
    }
#pragma unroll
    for (int o3 = 0; o3 < 9; ++o3) {
        float s = a3b[o3];
#pragma unroll
        for (int o2 = 0; o2 < 9; ++o2) s += a3w[o3 * 9 + o2] * t2[o2];
        attv[o3] = 1.f / (1.f + __expf(-s));
    }
#pragma unroll
    for (int p = 0; p < 9; ++p) att_s[p * 264 + tid] = f2bf(attv[p]);
    __syncthreads();

    // ---- main einsum: per chunk c, z = W_c · pat_c (zero-C MFMA), then
    //      acc += att * z as float4 vector math (-> v_pk_fma_f32)
    float4_ acc0[4], acc1[4];
#pragma unroll
    for (int g = 0; g < 4; ++g) { acc0[g] = zero4; acc1[g] = zero4; }
#pragma unroll
    for (int c = 0; c < 9; ++c) {
        short8 w0 = ((const short8*)wA)[c * 128 + lane];
        short8 w1 = ((const short8*)wA)[c * 128 + 64 + lane];
        const int coff = (c / 3) * 144 + (c % 3) * 8;
#pragma unroll
        for (int g = 0; g < 4; ++g) {
            short8 bP = *(const short8*)&xs[pb + g * 144 + coff];
            float av = bf2f(att_s[c * 264 + (wv * 4 + g) * 16 + tx]);
            float4_ av4 = {av, av, av, av};
            float4_ z0 = __builtin_amdgcn_mfma_f32_16x16x32_bf16(w0, bP, zero4, 0, 0, 0);
            float4_ z1 = __builtin_amdgcn_mfma_f32_16x16x32_bf16(w1, bP, zero4, 0, 0, 0);
            acc0[g] = acc0[g] + av4 * z0;
            acc1[g] = acc1[g] + av4 * z1;
        }
    }

    // ---- epilogue: D row = m = mt*16 + ks*4 + reg, col = tx ----
    const int wc = tw0 + tx;
    float4_ bv0 = *(const float4_*)&bias_lds[ks * 4];
    float4_ bv1 = *(const float4_*)&bias_lds[16 + ks * 4];
#pragma unroll
    for (int g = 0; g < 4; ++g) {
        int h = th0 + wv * 4 + g;
#pragma unroll
        for (int reg = 0; reg < 4; ++reg) {
            int m0 = ks * 4 + reg;
            out[((b * M_ + m0) * HW + h) * HW + wc] = acc0[g][reg] + bv0[reg];
            out[((b * M_ + m0 + 16) * HW + h) * HW + wc] = acc1[g][reg] + bv1[reg];
        }
    }
}

extern "C" void kernel_launch(void* const* d_in, const int* in_sizes, int n_in,
                              void* d_out, int out_size, void* d_ws,
                              size_t ws_size, hipStream_t stream) {
    const float* x   = (const float*)d_in[0];
    const float* a1w = (const float*)d_in[1];
    const float* a1b = (const float*)d_in[2];
    const float* a2w = (const float*)d_in[3];
    const float* a2b = (const float*)d_in[4];
    const float* a3w = (const float*)d_in[5];
    const float* a3b = (const float*)d_in[6];
    const float* b1w = (const float*)d_in[7];
    const float* b1b = (const float*)d_in[8];
    const float* b2w = (const float*)d_in[9];
    const float* b2b = (const float*)d_in[10];
    const float* wgt = (const float*)d_in[11];
    float* out = (float*)d_out;

    char* ws = (char*)d_ws;
    float* partial       = (float*)(ws);                   // 196608 B
    unsigned short* a1A  = (unsigned short*)(ws + 196608); //   9216 B
    unsigned short* wAf  = (unsigned short*)(ws + 205824); //  18432 B
    unsigned short* xt   = (unsigned short*)(ws + 262144); //  18.9 MB

    transpose_pool_kernel<<<dim3(B_ * HW + 1), dim3(192), 0, stream>>>(
        x, a1w, wgt, partial, a1A, wAf, xt);
    laconv_kernel<<<dim3(12 * 12 * B_), dim3(256), 0, stream>>>(
        xt, a1b, a2w, a2b, a3w, a3b, a1A, wAf, partial, b1w, b1b, b2w, b2b, out);
    (void)in_sizes; (void)n_in; (void)out_size; (void)ws_size;
}

// Round 9
// 150.812 us; speedup vs baseline: 1.0086x; 1.0086x over previous
//
#include <hip/hip_runtime.h>
#include <math.h>

#define B_ 8
#define N_ 32
#define M_ 32
#define HW 192

typedef __attribute__((ext_vector_type(8))) short short8;
typedef __attribute__((ext_vector_type(4))) float float4_;

__device__ inline unsigned short f2bf(float f) {
    unsigned int b = __float_as_uint(f);
    b += 0x7FFF + ((b >> 16) & 1);   // RNE
    return (unsigned short)(b >> 16);
}
__device__ inline float bf2f(unsigned short u) {
    return __uint_as_float((unsigned int)u << 16);
}

union U8 { short8 s; unsigned int u[4]; };

// ---- transpose+pool (blocks 0..1535, one per (b,h) row) + prep (block 1536) ----
// x_t[b][h][w][n] bf16 (channel-last); partial[b][h][n] = row sum
__global__ __launch_bounds__(192) void transpose_pool_kernel(
    const float* __restrict__ x, const float* __restrict__ a1w,
    const float* __restrict__ weight, float* __restrict__ partial,
    unsigned short* __restrict__ a1A, unsigned short* __restrict__ wA,
    unsigned short* __restrict__ xt) {
    const int id = blockIdx.x;
    const int tid = threadIdx.x;
    if (id == 1536) {  // prep block: build bf16 MFMA A-fragments
        for (int idx = tid; idx < 9 * 512; idx += 192) {
            int j = idx & 7, l = (idx >> 3) & 63, c = idx >> 9;
            int o = l & 15, n = (l >> 4) * 8 + j;
            float v = (o < 9) ? a1w[(o * N_ + n) * 9 + c] : 0.f;
            a1A[idx] = f2bf(v);
        }
        for (int idx = tid; idx < 9 * 1024; idx += 192) {
            int j = idx & 7, l = (idx >> 3) & 63, mt = (idx >> 9) & 1, c = idx >> 10;
            int m = mt * 16 + (l & 15), n = (l >> 4) * 8 + j;
            wA[idx] = f2bf(weight[(m * N_ + n) * 9 + c]);
        }
        return;
    }
    // b = id&7 keeps one image per XCD (matches laconv's consumer swizzle)
    const int b = id & 7, h = id >> 3;  // h in 0..191
    const float* xb = x + (size_t)b * N_ * (HW * HW) + h * HW + tid;
    float v[32];
#pragma unroll
    for (int n = 0; n < 32; ++n) v[n] = xb[n * (HW * HW)];
    U8 tq[4];
#pragma unroll
    for (int q = 0; q < 4; ++q)
#pragma unroll
        for (int i = 0; i < 4; ++i)
            tq[q].u[i] = (unsigned)f2bf(v[q * 8 + 2 * i]) |
                         ((unsigned)f2bf(v[q * 8 + 2 * i + 1]) << 16);
    short8* dst = (short8*)&xt[(((size_t)b * HW + h) * HW + tid) * 32];
    dst[0] = tq[0].s; dst[1] = tq[1].s; dst[2] = tq[2].s; dst[3] = tq[3].s;

    // per-channel row sums: wave shuffle reduce, then cross-wave via LDS
    __shared__ float red[3][32];
    const int wv = tid >> 6, lane = tid & 63;
#pragma unroll
    for (int n = 0; n < 32; ++n) {
        float s = v[n];
#pragma unroll
        for (int off = 32; off > 0; off >>= 1) s += __shfl_down(s, off, 64);
        if (lane == 0) red[wv][n] = s;
    }
    __syncthreads();
    if (tid < 32)
        partial[((size_t)b * HW + h) * 32 + tid] =
            red[0][tid] + red[1][tid] + red[2][tid];
}

// ---- bias: pooled = mean(partial rows); MLP 32->32->32; bias[b][m] ----
__global__ __launch_bounds__(256) void bias_kernel(
    const float* __restrict__ partial, const float* __restrict__ b1w,
    const float* __restrict__ b1b, const float* __restrict__ b2w,
    const float* __restrict__ b2b, float* __restrict__ bias) {
    const int tid = threadIdx.x;
    const int b = tid >> 5, j = tid & 31;
    float ps = 0.f;
#pragma unroll 8
    for (int h = 0; h < HW; ++h) ps += partial[((size_t)b * HW + h) * 32 + j];
    __shared__ float pooled_s[B_][32], hsh[B_][32];
    pooled_s[b][j] = ps * (1.f / (HW * HW));
    __syncthreads();
    float s = b1b[j];
#pragma unroll
    for (int n = 0; n < N_; ++n) s += pooled_s[b][n] * b1w[j * N_ + n];
    hsh[b][j] = fmaxf(s, 0.f);
    __syncthreads();
    float s2 = b2b[j];
#pragma unroll
    for (int q = 0; q < M_; ++q) s2 += hsh[b][q] * b2w[j * M_ + q];
    bias[b * M_ + j] = s2;
}

// ---------- fused MFMA kernel: attention1 + attended conv + bias ----------
// 8x32 tiles: each block owns full 128-B output lines (write-combine fix)
__global__ __launch_bounds__(256) void laconv_kernel(
    const unsigned short* __restrict__ xt, const float* __restrict__ a1b,
    const float* __restrict__ a2w, const float* __restrict__ a2b,
    const float* __restrict__ a3w, const float* __restrict__ a3b,
    const unsigned short* __restrict__ a1A, const unsigned short* __restrict__ wA,
    const float* __restrict__ bias, float* __restrict__ out) {
    // xs[grp][pos][j]: grp = n/8 (stride 2728 shorts, padded), pos = r*34+cc
    // (10x34 halo tile), j = n%8
    __shared__ __align__(16) unsigned short xs[4 * 2728];  // 21824 B
    __shared__ unsigned short att_s[9 * 264];              //  4752 B -> 6 blk/CU

    // XCD-affinity swizzle: batch = id&7, tiles of one image stay per-XCD
    const int id = blockIdx.x;
    const int b = id & 7;
    const int t = id >> 3;               // 0..143
    const int bx = t % 6, by = t / 6;    // 6 x 24 tiles of 32w x 8h
    const int th0 = by * 8, tw0 = bx * 32;
    const int tid = threadIdx.x;
    const int wv = tid >> 6, lane = tid & 63;
    const int tx = lane & 15, ks = lane >> 4;

    // early per-lane bias load into registers (L2-hot, off the barrier path)
    float4_ bv0 = *(const float4_*)&bias[b * M_ + ks * 4];
    float4_ bv1 = *(const float4_*)&bias[b * M_ + 16 + ks * 4];

    // ---- stage: 64B bf16 channel rows from x_t -> xs (no conversion) ----
    const unsigned short* xtb = xt + (size_t)b * (HW * HW) * 32;
    short8 ra[4], rb[4];
    {
        int pos = tid, r = pos / 34, cc = pos - r * 34;
        int h = th0 + r - 1, w = tw0 + cc - 1;
        if (((unsigned)h < HW) && ((unsigned)w < HW)) {
            const short8* src = (const short8*)&xtb[(size_t)(h * HW + w) * 32];
            ra[0] = src[0]; ra[1] = src[1]; ra[2] = src[2]; ra[3] = src[3];
        } else {
#pragma unroll
            for (int g = 0; g < 4; ++g) ra[g] = (short8)(short)0;
        }
    }
    const bool hasB = tid < 340 - 256;
    if (hasB) {
        int pos = 256 + tid, r = pos / 34, cc = pos - r * 34;
        int h = th0 + r - 1, w = tw0 + cc - 1;
        if (((unsigned)h < HW) && ((unsigned)w < HW)) {
            const short8* src = (const short8*)&xtb[(size_t)(h * HW + w) * 32];
            rb[0] = src[0]; rb[1] = src[1]; rb[2] = src[2]; rb[3] = src[3];
        } else {
#pragma unroll
            for (int g = 0; g < 4; ++g) rb[g] = (short8)(short)0;
        }
    }
#pragma unroll
    for (int g = 0; g < 4; ++g) *(short8*)&xs[g * 2728 + tid * 8] = ra[g];
    if (hasB) {
#pragma unroll
        for (int g = 0; g < 4; ++g) *(short8*)&xs[g * 2728 + (256 + tid) * 8] = rb[g];
    }
    __syncthreads();

    // per-group pixel mapping: gi = wv*4+g; pixel = gi*16+tx
    // -> tile row h8 = gi>>1, col = (gi&1)*16 + tx
    int pbg[4];
#pragma unroll
    for (int g = 0; g < 4; ++g) {
        int gi = wv * 4 + g;
        pbg[g] = ks * 2728 + (((gi >> 1)) * 34 + ((gi & 1) << 4) + tx) * 8;
    }
    const float4_ zero4 = {0.f, 0.f, 0.f, 0.f};

    // ---- attention1 conv via MFMA: aacc[o=ks*4+reg][pix] per group ----
    float4_ aacc[4];
#pragma unroll
    for (int g = 0; g < 4; ++g) aacc[g] = zero4;
#pragma unroll
    for (int c = 0; c < 9; ++c) {
        short8 aA = ((const short8*)a1A)[c * 64 + lane];
        const int coff = (c / 3) * 272 + (c % 3) * 8;   // dr*34*8 + dc*8
#pragma unroll
        for (int g = 0; g < 4; ++g) {
            short8 bP = *(const short8*)&xs[pbg[g] + coff];
            aacc[g] = __builtin_amdgcn_mfma_f32_16x16x32_bf16(aA, bP, aacc[g], 0, 0, 0);
        }
    }
#pragma unroll
    for (int g = 0; g < 4; ++g) {
#pragma unroll
        for (int reg = 0; reg < 4; ++reg) {
            int o = ks * 4 + reg;
            if (o < 9) att_s[o * 264 + (wv * 4 + g) * 16 + tx] = f2bf(aacc[g][reg]);
        }
    }
    __syncthreads();

    // ---- per-pixel MLP 9->9->9 + sigmoid; column-local, no extra barrier ----
    float t1[9], t2[9], attv[9];
#pragma unroll
    for (int o = 0; o < 9; ++o)
        t1[o] = fmaxf(bf2f(att_s[o * 264 + tid]) + a1b[o], 0.f);
#pragma unroll
    for (int o2 = 0; o2 < 9; ++o2) {
        float s = a2b[o2];
#pragma unroll
        for (int o = 0; o < 9; ++o) s += a2w[o2 * 9 + o] * t1[o];
        t2[o2] = fmaxf(s, 0.f);
    }
#pragma unroll
    for (int o3 = 0; o3 < 9; ++o3) {
        float s = a3b[o3];
#pragma unroll
        for (int o2 = 0; o2 < 9; ++o2) s += a3w[o3 * 9 + o2] * t2[o2];
        attv[o3] = 1.f / (1.f + __expf(-s));
    }
#pragma unroll
    for (int p = 0; p < 9; ++p) att_s[p * 264 + tid] = f2bf(attv[p]);
    __syncthreads();

    // ---- main einsum: per chunk c, z = W_c · pat_c (zero-C MFMA), then
    //      acc += att * z as float4 vector math (-> v_pk_fma_f32)
    float4_ acc0[4], acc1[4];
#pragma unroll
    for (int g = 0; g < 4; ++g) { acc0[g] = zero4; acc1[g] = zero4; }
#pragma unroll
    for (int c = 0; c < 9; ++c) {
        short8 w0 = ((const short8*)wA)[c * 128 + lane];
        short8 w1 = ((const short8*)wA)[c * 128 + 64 + lane];
        const int coff = (c / 3) * 272 + (c % 3) * 8;
#pragma unroll
        for (int g = 0; g < 4; ++g) {
            short8 bP = *(const short8*)&xs[pbg[g] + coff];
            float av = bf2f(att_s[c * 264 + (wv * 4 + g) * 16 + tx]);
            float4_ av4 = {av, av, av, av};
            float4_ z0 = __builtin_amdgcn_mfma_f32_16x16x32_bf16(w0, bP, zero4, 0, 0, 0);
            float4_ z1 = __builtin_amdgcn_mfma_f32_16x16x32_bf16(w1, bP, zero4, 0, 0, 0);
            acc0[g] = acc0[g] + av4 * z0;
            acc1[g] = acc1[g] + av4 * z1;
        }
    }

    // ---- epilogue: row m = mt*16+ks*4+reg, col = pixel; full-line writes ----
#pragma unroll
    for (int g = 0; g < 4; ++g) {
        int gi = wv * 4 + g;
        int h = th0 + (gi >> 1);
        int wc = tw0 + ((gi & 1) << 4) + tx;
#pragma unroll
        for (int reg = 0; reg < 4; ++reg) {
            int m0 = ks * 4 + reg;
            out[((b * M_ + m0) * HW + h) * HW + wc] = acc0[g][reg] + bv0[reg];
            out[((b * M_ + m0 + 16) * HW + h) * HW + wc] = acc1[g][reg] + bv1[reg];
        }
    }
}

extern "C" void kernel_launch(void* const* d_in, const int* in_sizes, int n_in,
                              void* d_out, int out_size, void* d_ws,
                              size_t ws_size, hipStream_t stream) {
    const float* x   = (const float*)d_in[0];
    const float* a1w = (const float*)d_in[1];
    const float* a1b = (const float*)d_in[2];
    const float* a2w = (const float*)d_in[3];
    const float* a2b = (const float*)d_in[4];
    const float* a3w = (const float*)d_in[5];
    const float* a3b = (const float*)d_in[6];
    const float* b1w = (const float*)d_in[7];
    const float* b1b = (const float*)d_in[8];
    const float* b2w = (const float*)d_in[9];
    const float* b2b = (const float*)d_in[10];
    const float* wgt = (const float*)d_in[11];
    float* out = (float*)d_out;

    char* ws = (char*)d_ws;
    float* partial       = (float*)(ws);                   // 196608 B
    unsigned short* a1A  = (unsigned short*)(ws + 196608); //   9216 B
    unsigned short* wAf  = (unsigned short*)(ws + 205824); //  18432 B
    float* biasv         = (float*)(ws + 224256);          //   1024 B
    unsigned short* xt   = (unsigned short*)(ws + 262144); //  18.9 MB

    transpose_pool_kernel<<<dim3(B_ * HW + 1), dim3(192), 0, stream>>>(
        x, a1w, wgt, partial, a1A, wAf, xt);
    bias_kernel<<<dim3(1), dim3(256), 0, stream>>>(partial, b1w, b1b, b2w, b2b,
                                                   biasv);
    laconv_kernel<<<dim3(12 * 12 * B_), dim3(256), 0, stream>>>(
        xt, a1b, a2w, a2b, a3w, a3b, a1A, wAf, biasv, out);
    (void)in_sizes; (void)n_in; (void)out_size; (void)ws_size;
}